// Round 5
// baseline (112.994 us; speedup 1.0000x reference)
//
#include <hip/hip_runtime.h>
#include <hip/hip_bf16.h>

typedef __attribute__((ext_vector_type(8))) short short8;
typedef __attribute__((ext_vector_type(4))) float f32x4;

#define MFMA16(a, b, c) __builtin_amdgcn_mfma_f32_16x16x32_bf16((a), (b), (c), 0, 0, 0)

__device__ __forceinline__ short f2bf(float f) {
  union { float f; unsigned u; } v; v.f = f;
  unsigned r = v.u + 0x7fffu + ((v.u >> 16) & 1u);   // RNE to bf16
  return (short)(r >> 16);
}
__device__ __forceinline__ unsigned pack2(float lo, float hi) {
  return (unsigned)(unsigned short)f2bf(lo) | ((unsigned)(unsigned short)f2bf(hi) << 16);
}

// ---------------------------------------------------------------------------
// K1: QKV projection.  Out[e][pix] = W[e][c] · x[c][pix] + b[e], bf16 outputs.
// (unchanged — ~31µs vs ~25µs memory floor; revisit after K2)
// ---------------------------------------------------------------------------
__global__ __launch_bounds__(256) void qkv_kernel(
    const float* __restrict__ x,
    const float* __restrict__ wq, const float* __restrict__ bq,
    const float* __restrict__ wk, const float* __restrict__ bk,
    const float* __restrict__ wv, const float* __restrict__ bv,
    short* __restrict__ Q, short* __restrict__ K, short* __restrict__ V)
{
  __shared__ alignas(16) short xs[64 * 256];     // [c][pix], linear, 32KB
  __shared__ alignas(16) short ws[3 * 64 * 64];  // [m][e][c ^ ((e&7)<<3)], 24KB
  __shared__ float bs[3 * 64];

  const int t    = threadIdx.x;
  const int b    = blockIdx.x >> 6;
  const int pt   = blockIdx.x & 63;
  const int pix0 = pt << 8;
  const float* xb = x + ((size_t)b << 20);

  #pragma unroll
  for (int i = 0; i < 16; ++i) {
    int f4 = i * 256 + t;
    int c  = f4 >> 6;
    int p4 = (f4 & 63) << 2;
    const float4 v = *reinterpret_cast<const float4*>(xb + c * 16384 + pix0 + p4);
    short* d = &xs[c * 256 + p4];
    d[0] = f2bf(v.x); d[1] = f2bf(v.y); d[2] = f2bf(v.z); d[3] = f2bf(v.w);
  }
  {
    #pragma unroll
    for (int i = 0; i < 16; ++i) {
      int idx = i * 256 + t;
      int e = idx >> 6, c = idx & 63;
      int d = e * 64 + (c ^ ((e & 7) << 3));
      ws[d]        = f2bf(wq[idx]);
      ws[d + 4096] = f2bf(wk[idx]);
      ws[d + 8192] = f2bf(wv[idx]);
    }
    if (t < 192) bs[t] = (t < 64) ? bq[t] : ((t < 128) ? bk[t - 64] : bv[t - 128]);
  }
  __syncthreads();

  const int lane = t & 63;
  const int wid  = t >> 6;
  const int p0   = wid << 6;
  const int l15  = lane & 15;
  const int lg   = lane >> 4;

  short8 bfrag[4][2];
  #pragma unroll
  for (int nt = 0; nt < 4; ++nt) {
    int pix = p0 + nt * 16 + l15;
    #pragma unroll
    for (int ks = 0; ks < 2; ++ks) {
      int cb = ks * 32 + (lg << 3);
      short8 f;
      #pragma unroll
      for (int j = 0; j < 8; ++j) f[j] = xs[(cb + j) * 256 + pix];
      bfrag[nt][ks] = f;
    }
  }

  #pragma unroll
  for (int m = 0; m < 3; ++m) {
    short* op = (m == 0) ? Q : ((m == 1) ? K : V);
    short8 afrag[4][2];
    #pragma unroll
    for (int mt = 0; mt < 4; ++mt) {
      int e = mt * 16 + l15;
      #pragma unroll
      for (int ks = 0; ks < 2; ++ks) {
        int cb8 = (ks * 4 + lg) ^ (e & 7);
        afrag[mt][ks] = *reinterpret_cast<const short8*>(&ws[m * 4096 + e * 64 + cb8 * 8]);
      }
    }
    #pragma unroll
    for (int mt = 0; mt < 4; ++mt) {
      #pragma unroll
      for (int nt = 0; nt < 4; ++nt) {
        f32x4 acc = {0.f, 0.f, 0.f, 0.f};
        acc = MFMA16(afrag[mt][0], bfrag[nt][0], acc);
        acc = MFMA16(afrag[mt][1], bfrag[nt][1], acc);
        int e_base = mt * 16 + (lg << 2);
        int pix = pix0 + p0 + nt * 16 + l15;
        #pragma unroll
        for (int r = 0; r < 4; ++r) {
          int e = e_base + r;
          float val = acc[r] + bs[m * 64 + e];
          op[(((size_t)b * 64 + e) << 14) + pix] = f2bf(val);
        }
      }
    }
  }
}

// ---------------------------------------------------------------------------
// K2: per-(b,e) attention.  512 thr = 8 waves, 16-row strip each.
// 64KB LDS (2 x 32KB) -> 2 blocks/CU.  row&15 XOR swizzle (granule-level)
// so strip stores are conflict-free.  Q/K transposed IN-PLACE in LDS
// (col-gather to packed regs -> barrier -> b128 rows).  V column-gathered
// from global into regs during S1/S2 (latency hidden), written as VT when
// KT dies.
//   B1: Q -> QT -> T1 -> TV      B2: K -> KT -> VT -> T2^T
// ---------------------------------------------------------------------------
__global__ __launch_bounds__(512, 4) void attn_kernel(
    const short* __restrict__ Qg, const short* __restrict__ Kg,
    const short* __restrict__ Vg, float* __restrict__ out)
{
  __shared__ alignas(16) short B1[128 * 128];    // 32KB
  __shared__ alignas(16) short B2[128 * 128];    // 32KB

  const int t = threadIdx.x;
  const size_t base = (size_t)blockIdx.x << 14;  // (b*64+e)*16384

  // coalesced global rows -> swizzled LDS rows
  auto stage = [&](short* dst, const short* src) {
    #pragma unroll
    for (int i = 0; i < 4; ++i) {
      int eb  = i * 512 + t;                     // 16B granule id
      int row = eb >> 4;
      int cb  = eb & 15;
      float4 v = *reinterpret_cast<const float4*>(src + (eb << 3));
      *reinterpret_cast<float4*>(dst + row * 128 + ((cb ^ (row & 15)) << 3)) = v;
    }
  };

  const int w  = t & 127;        // transpose: owned column
  const int rb = (t >> 7) << 5;  // transpose: row-block base (0/32/64/96)

  // column gather from swizzled LDS tile -> 16 packed bf16 pairs
  auto t_read = [&](const short* src, unsigned* p) {
    #pragma unroll
    for (int k2 = 0; k2 < 16; ++k2) {
      int r0 = rb + 2 * k2;
      int r1 = r0 + 1;
      unsigned a  = (unsigned short)src[r0 * 128 + (w ^ ((r0 & 15) << 3))];
      unsigned b_ = (unsigned short)src[r1 * 128 + (w ^ ((r1 & 15) << 3))];
      p[k2] = a | (b_ << 16);
    }
  };
  // packed col regs -> transposed row in dst (b128, swizzled)
  auto t_write = [&](short* dst, const unsigned* p) {
    const int w15 = w & 15;
    #pragma unroll
    for (int k8 = 0; k8 < 4; ++k8) {
      int hb = (rb >> 3) + k8;
      *reinterpret_cast<short8*>(&dst[w * 128 + ((hb ^ w15) << 3)]) =
          *reinterpret_cast<const short8*>(&p[k8 * 4]);
    }
  };

  const int lane = t & 63;
  const int wid  = t >> 6;      // 0..7
  const int m0   = wid << 4;    // own 16-row output strip
  const int l15  = lane & 15;
  const int lg   = lane >> 4;

  auto ldfrag = [&](const short* buf, int rowbase, int ks) -> short8 {
    int row = rowbase + l15;
    int cb  = (ks * 4 + lg) ^ (row & 15);
    return *reinterpret_cast<const short8*>(&buf[row * 128 + cb * 8]);
  };

  f32x4 acc[8];

  auto matmul = [&](const short* bufA, const short* bufB) {
    short8 af[4];
    #pragma unroll
    for (int ks = 0; ks < 4; ++ks) af[ks] = ldfrag(bufA, m0, ks);
    #pragma unroll
    for (int n = 0; n < 8; ++n) {
      f32x4 a = {0.f, 0.f, 0.f, 0.f};
      #pragma unroll
      for (int ks = 0; ks < 4; ++ks) a = MFMA16(af[ks], ldfrag(bufB, n * 16, ks), a);
      acc[n] = a;
    }
  };

  auto softmax_pack = [&](unsigned* pk) {
    #pragma unroll
    for (int r = 0; r < 4; ++r) {
      float mx = acc[0][r];
      #pragma unroll
      for (int n = 1; n < 8; ++n) mx = fmaxf(mx, acc[n][r]);
      mx = fmaxf(mx, __shfl_xor(mx, 1));
      mx = fmaxf(mx, __shfl_xor(mx, 2));
      mx = fmaxf(mx, __shfl_xor(mx, 4));
      mx = fmaxf(mx, __shfl_xor(mx, 8));
      float p[8]; float s = 0.f;
      #pragma unroll
      for (int n = 0; n < 8; ++n) { p[n] = __expf((acc[n][r] - mx) * 0.125f); s += p[n]; }
      s += __shfl_xor(s, 1); s += __shfl_xor(s, 2);
      s += __shfl_xor(s, 4); s += __shfl_xor(s, 8);
      float inv = 1.0f / s;
      #pragma unroll
      for (int np = 0; np < 4; ++np)
        pk[r * 4 + np] = pack2(p[2 * np] * inv, p[2 * np + 1] * inv);
    }
  };

  // packed strip -> own 16 rows (row&15 swizzle -> ~2-way, free)
  auto store_pk = [&](short* dst, const unsigned* pk) {
    #pragma unroll
    for (int r = 0; r < 4; ++r) {
      int row = m0 + (lg << 2) + r;
      int sw  = (row & 15) << 3;
      #pragma unroll
      for (int np = 0; np < 4; ++np) {
        unsigned v = pk[r * 4 + np];
        int c0 = (2 * np) * 16 + l15;
        int c1 = c0 + 16;
        dst[row * 128 + (c0 ^ sw)] = (short)(v & 0xffff);
        dst[row * 128 + (c1 ^ sw)] = (short)(v >> 16);
      }
    }
  };

  unsigned t1[16], t2[16];
  unsigned qr[16], kr[16], vr[16];

  // 1. stage Q, K
  stage(B1, Qg + base);
  stage(B2, Kg + base);
  __syncthreads();                               // b0

  // 2. S1 = Q K^T -> softmax -> t1; gather Q/K cols (LDS) + V cols (global)
  matmul(B1, B2);
  softmax_pack(t1);
  t_read(B1, qr);
  t_read(B2, kr);
  {
    const short* Vsrc = Vg + base;
    #pragma unroll
    for (int k2 = 0; k2 < 16; ++k2) {
      unsigned a  = (unsigned short)Vsrc[(rb + 2 * k2) * 128 + w];
      unsigned b_ = (unsigned short)Vsrc[(rb + 2 * k2 + 1) * 128 + w];
      vr[k2] = a | (b_ << 16);
    }
  }
  __syncthreads();                               // b1: all B1/B2 reads done

  // 3. in-place transpose: B1=QT, B2=KT
  t_write(B1, qr);
  t_write(B2, kr);
  __syncthreads();                               // b2

  // 4. S2^T = K^T Q -> softmax -> t2   (A=KT strips, B=QT)
  matmul(B2, B1);
  softmax_pack(t2);
  __syncthreads();                               // b3: S2 reads done

  // 5. T1 -> B1; VT -> B2 (from prefetched regs)
  store_pk(B1, t1);
  t_write(B2, vr);
  __syncthreads();                               // b4

  // 6. TV = T1 · V (B-frags = rows of VT); TV -> own strip of B1 (safe)
  matmul(B1, B2);
  #pragma unroll
  for (int n = 0; n < 8; ++n) {
    #pragma unroll
    for (int r = 0; r < 4; ++r) {
      int row = m0 + (lg << 2) + r;
      int col = n * 16 + l15;
      B1[row * 128 + (col ^ ((row & 15) << 3))] = f2bf(acc[n][r]);
    }
  }
  __syncthreads();                               // b5: TV's B2 reads done

  // 7. T2^T -> B2
  store_pk(B2, t2);
  __syncthreads();                               // b6

  // 8. OUT = TV · T2 -> fp32 global
  float* ob = out + base;
  #pragma unroll
  for (int n = 0; n < 8; ++n) {
    f32x4 a = {0.f, 0.f, 0.f, 0.f};
    #pragma unroll
    for (int ks = 0; ks < 4; ++ks)
      a = MFMA16(ldfrag(B1, m0, ks), ldfrag(B2, n * 16, ks), a);
    #pragma unroll
    for (int r = 0; r < 4; ++r) {
      int row = m0 + (lg << 2) + r;
      ob[row * 128 + n * 16 + l15] = a[r];
    }
  }
}

extern "C" void kernel_launch(void* const* d_in, const int* in_sizes, int n_in,
                              void* d_out, int out_size, void* d_ws, size_t ws_size,
                              hipStream_t stream) {
  const float* x  = (const float*)d_in[0];
  const float* wq = (const float*)d_in[1];
  const float* bq = (const float*)d_in[2];
  const float* wk = (const float*)d_in[3];
  const float* bk = (const float*)d_in[4];
  const float* wv = (const float*)d_in[5];
  const float* bv = (const float*)d_in[6];

  const size_t N = (size_t)16 * 64 * 128 * 128;
  short* Q = (short*)d_ws;
  short* K = Q + N;
  short* V = K + N;

  qkv_kernel<<<1024, 256, 0, stream>>>(x, wq, bq, wk, bk, wv, bv, Q, K, V);
  attn_kernel<<<1024, 512, 0, stream>>>(Q, K, V, (float*)d_out);
}

// Round 7
// 108.957 us; speedup vs baseline: 1.0371x; 1.0371x over previous
//
#include <hip/hip_runtime.h>
#include <hip/hip_bf16.h>

typedef __attribute__((ext_vector_type(8))) short short8;
typedef __attribute__((ext_vector_type(4))) float f32x4;

#define MFMA16(a, b, c) __builtin_amdgcn_mfma_f32_16x16x32_bf16((a), (b), (c), 0, 0, 0)

__device__ __forceinline__ short f2bf(float f) {
  union { float f; unsigned u; } v; v.f = f;
  unsigned r = v.u + 0x7fffu + ((v.u >> 16) & 1u);   // RNE to bf16
  return (short)(r >> 16);
}

// ---------------------------------------------------------------------------
// K1: QKV projection (unchanged — ~30µs vs ~25µs floor)
// ---------------------------------------------------------------------------
__global__ __launch_bounds__(256) void qkv_kernel(
    const float* __restrict__ x,
    const float* __restrict__ wq, const float* __restrict__ bq,
    const float* __restrict__ wk, const float* __restrict__ bk,
    const float* __restrict__ wv, const float* __restrict__ bv,
    short* __restrict__ Q, short* __restrict__ K, short* __restrict__ V)
{
  __shared__ alignas(16) short xs[64 * 256];
  __shared__ alignas(16) short ws[3 * 64 * 64];
  __shared__ float bs[3 * 64];

  const int t    = threadIdx.x;
  const int b    = blockIdx.x >> 6;
  const int pt   = blockIdx.x & 63;
  const int pix0 = pt << 8;
  const float* xb = x + ((size_t)b << 20);

  #pragma unroll
  for (int i = 0; i < 16; ++i) {
    int f4 = i * 256 + t;
    int c  = f4 >> 6;
    int p4 = (f4 & 63) << 2;
    const float4 v = *reinterpret_cast<const float4*>(xb + c * 16384 + pix0 + p4);
    short* d = &xs[c * 256 + p4];
    d[0] = f2bf(v.x); d[1] = f2bf(v.y); d[2] = f2bf(v.z); d[3] = f2bf(v.w);
  }
  {
    #pragma unroll
    for (int i = 0; i < 16; ++i) {
      int idx = i * 256 + t;
      int e = idx >> 6, c = idx & 63;
      int d = e * 64 + (c ^ ((e & 7) << 3));
      ws[d]        = f2bf(wq[idx]);
      ws[d + 4096] = f2bf(wk[idx]);
      ws[d + 8192] = f2bf(wv[idx]);
    }
    if (t < 192) bs[t] = (t < 64) ? bq[t] : ((t < 128) ? bk[t - 64] : bv[t - 128]);
  }
  __syncthreads();

  const int lane = t & 63;
  const int wid  = t >> 6;
  const int p0   = wid << 6;
  const int l15  = lane & 15;
  const int lg   = lane >> 4;

  short8 bfrag[4][2];
  #pragma unroll
  for (int nt = 0; nt < 4; ++nt) {
    int pix = p0 + nt * 16 + l15;
    #pragma unroll
    for (int ks = 0; ks < 2; ++ks) {
      int cb = ks * 32 + (lg << 3);
      short8 f;
      #pragma unroll
      for (int j = 0; j < 8; ++j) f[j] = xs[(cb + j) * 256 + pix];
      bfrag[nt][ks] = f;
    }
  }

  #pragma unroll
  for (int m = 0; m < 3; ++m) {
    short* op = (m == 0) ? Q : ((m == 1) ? K : V);
    short8 afrag[4][2];
    #pragma unroll
    for (int mt = 0; mt < 4; ++mt) {
      int e = mt * 16 + l15;
      #pragma unroll
      for (int ks = 0; ks < 2; ++ks) {
        int cb8 = (ks * 4 + lg) ^ (e & 7);
        afrag[mt][ks] = *reinterpret_cast<const short8*>(&ws[m * 4096 + e * 64 + cb8 * 8]);
      }
    }
    #pragma unroll
    for (int mt = 0; mt < 4; ++mt) {
      #pragma unroll
      for (int nt = 0; nt < 4; ++nt) {
        f32x4 acc = {0.f, 0.f, 0.f, 0.f};
        acc = MFMA16(afrag[mt][0], bfrag[nt][0], acc);
        acc = MFMA16(afrag[mt][1], bfrag[nt][1], acc);
        int e_base = mt * 16 + (lg << 2);
        int pix = pix0 + p0 + nt * 16 + l15;
        #pragma unroll
        for (int r = 0; r < 4; ++r) {
          int e = e_base + r;
          float val = acc[r] + bs[m * 64 + e];
          op[(((size_t)b * 64 + e) << 14) + pix] = f2bf(val);
        }
      }
    }
  }
}

// ---------------------------------------------------------------------------
// K2: per-(b,e) attention.  r3 structure (low liveness, in-LDS transposes,
// 4 x 32KB buffers) + conflict-free row&15 granule swizzle + V prefetched
// into 16 VGPRs under the transpose phase.
//   B1: Q -> T1 -> TV    B2: K -> V    B3: KT -> VT    B4: QT -> T2^T
// ---------------------------------------------------------------------------
__global__ __launch_bounds__(512) void attn_kernel(
    const short* __restrict__ Qg, const short* __restrict__ Kg,
    const short* __restrict__ Vg, float* __restrict__ out)
{
  __shared__ alignas(16) short lds[4 * 16384];   // 128KB
  short* B1 = lds;
  short* B2 = lds + 16384;
  short* B3 = lds + 2 * 16384;
  short* B4 = lds + 3 * 16384;

  const int t = threadIdx.x;
  const size_t base = (size_t)blockIdx.x << 14;

  // coalesced global rows -> swizzled LDS rows
  auto stage = [&](short* dst, const short* src) {
    #pragma unroll
    for (int i = 0; i < 4; ++i) {
      int eb  = i * 512 + t;
      int row = eb >> 4;
      int cb  = eb & 15;
      float4 v = *reinterpret_cast<const float4*>(src + (eb << 3));
      *reinterpret_cast<float4*>(dst + row * 128 + ((cb ^ (row & 15)) << 3)) = v;
    }
  };

  const int w  = t & 127;        // transpose: owned column
  const int rb = (t >> 7) << 5;  // transpose: row-block base (0/32/64/96)

  // dst[w][h] = src[h][w]; reads sweep consecutive cols (free), writes b128
  auto buildT = [&](short* dst, const short* src) {
    short v[32];
    #pragma unroll
    for (int k = 0; k < 32; ++k) {
      int r = rb + k;
      v[k] = src[r * 128 + (w ^ ((r & 15) << 3))];
    }
    const int w15 = w & 15;
    #pragma unroll
    for (int k8 = 0; k8 < 4; ++k8) {
      int hb = (rb >> 3) + k8;
      *reinterpret_cast<short8*>(&dst[w * 128 + ((hb ^ w15) << 3)]) =
          *reinterpret_cast<const short8*>(&v[k8 * 8]);
    }
  };

  const int lane = t & 63;
  const int wid  = t >> 6;
  const int m0   = wid << 4;
  const int l15  = lane & 15;
  const int lg   = lane >> 4;

  auto ldfrag = [&](const short* buf, int rowbase, int ks) -> short8 {
    int row = rowbase + l15;
    int cb  = (ks * 4 + lg) ^ (row & 15);
    return *reinterpret_cast<const short8*>(&buf[row * 128 + cb * 8]);
  };

  f32x4 acc[8];

  auto matmul = [&](const short* bufA, const short* bufB) {
    short8 af[4];
    #pragma unroll
    for (int ks = 0; ks < 4; ++ks) af[ks] = ldfrag(bufA, m0, ks);
    #pragma unroll
    for (int n = 0; n < 8; ++n) {
      f32x4 a = {0.f, 0.f, 0.f, 0.f};
      #pragma unroll
      for (int ks = 0; ks < 4; ++ks) a = MFMA16(af[ks], ldfrag(bufB, n * 16, ks), a);
      acc[n] = a;
    }
  };

  auto softmax_inplace = [&]() {
    #pragma unroll
    for (int r = 0; r < 4; ++r) {
      float mx = acc[0][r];
      #pragma unroll
      for (int n = 1; n < 8; ++n) mx = fmaxf(mx, acc[n][r]);
      mx = fmaxf(mx, __shfl_xor(mx, 1));
      mx = fmaxf(mx, __shfl_xor(mx, 2));
      mx = fmaxf(mx, __shfl_xor(mx, 4));
      mx = fmaxf(mx, __shfl_xor(mx, 8));
      float p[8]; float s = 0.f;
      #pragma unroll
      for (int n = 0; n < 8; ++n) { p[n] = __expf((acc[n][r] - mx) * 0.125f); s += p[n]; }
      s += __shfl_xor(s, 1); s += __shfl_xor(s, 2);
      s += __shfl_xor(s, 4); s += __shfl_xor(s, 8);
      float inv = 1.0f / s;
      #pragma unroll
      for (int n = 0; n < 8; ++n) acc[n][r] = p[n] * inv;
    }
  };

  // acc (bf16) -> own 16-row strip, conflict-free swizzle
  auto store_strip = [&](short* dst) {
    #pragma unroll
    for (int n = 0; n < 8; ++n) {
      #pragma unroll
      for (int r = 0; r < 4; ++r) {
        int row = m0 + (lg << 2) + r;
        int col = n * 16 + l15;
        dst[row * 128 + (col ^ ((row & 15) << 3))] = f2bf(acc[n][r]);
      }
    }
  };

  // 1. stage Q, K
  stage(B1, Qg + base);
  stage(B2, Kg + base);
  __syncthreads();                               // sync0

  // 2. S1 = Q K^T -> softmax (held in acc)
  matmul(B1, B2);
  softmax_inplace();
  __syncthreads();                               // sync_a: S1 reads done

  // 3. V prefetch (issue loads; latency hides under transposes), build QT/KT
  float4 vr[4];
  {
    const short* Vsrc = Vg + base;
    #pragma unroll
    for (int i = 0; i < 4; ++i)
      vr[i] = *reinterpret_cast<const float4*>(Vsrc + ((i * 512 + t) << 3));
  }
  buildT(B4, B1);                                // QT
  buildT(B3, B2);                                // KT
  __syncthreads();                               // sync_b

  // 4. T1 -> B1; V (regs) -> B2
  store_strip(B1);
  #pragma unroll
  for (int i = 0; i < 4; ++i) {
    int eb  = i * 512 + t;
    int row = eb >> 4;
    int cb  = eb & 15;
    *reinterpret_cast<float4*>(B2 + row * 128 + ((cb ^ (row & 15)) << 3)) = vr[i];
  }

  // 5. S2^T = K^T Q -> softmax (held in acc)
  matmul(B3, B4);
  softmax_inplace();
  __syncthreads();                               // sync_c: S2 reads + T1/V writes done

  // 6. T2^T -> B4; VT -> B3
  store_strip(B4);
  buildT(B3, B2);
  __syncthreads();                               // sync_d

  // 7. TV = T1 · V (A: B1 own strip, B: VT) -> own strip of B1
  matmul(B1, B3);
  store_strip(B1);

  // 8. OUT = TV · T2 = TV · (T2^T)^T -> fp32 global (B4 fenced by sync_d,
  //    B1 A-frags are own-strip so no barrier needed after store)
  float* ob = out + base;
  #pragma unroll
  for (int n = 0; n < 8; ++n) {
    f32x4 a = {0.f, 0.f, 0.f, 0.f};
    #pragma unroll
    for (int ks = 0; ks < 4; ++ks)
      a = MFMA16(ldfrag(B1, m0, ks), ldfrag(B4, n * 16, ks), a);
    #pragma unroll
    for (int r = 0; r < 4; ++r) {
      int row = m0 + (lg << 2) + r;
      ob[row * 128 + n * 16 + l15] = a[r];
    }
  }
}

extern "C" void kernel_launch(void* const* d_in, const int* in_sizes, int n_in,
                              void* d_out, int out_size, void* d_ws, size_t ws_size,
                              hipStream_t stream) {
  const float* x  = (const float*)d_in[0];
  const float* wq = (const float*)d_in[1];
  const float* bq = (const float*)d_in[2];
  const float* wk = (const float*)d_in[3];
  const float* bk = (const float*)d_in[4];
  const float* wv = (const float*)d_in[5];
  const float* bv = (const float*)d_in[6];

  const size_t N = (size_t)16 * 64 * 128 * 128;
  short* Q = (short*)d_ws;
  short* K = Q + N;
  short* V = K + N;

  qkv_kernel<<<1024, 256, 0, stream>>>(x, wq, bq, wk, bk, wv, bv, Q, K, V);
  attn_kernel<<<1024, 512, 0, stream>>>(Q, K, V, (float*)d_out);
}

// Round 8
// 88.542 us; speedup vs baseline: 1.2762x; 1.2306x over previous
//
#include <hip/hip_runtime.h>
#include <hip/hip_bf16.h>

typedef __attribute__((ext_vector_type(8))) short short8;
typedef __attribute__((ext_vector_type(4))) float f32x4;

#define MFMA16(a, b, c) __builtin_amdgcn_mfma_f32_16x16x32_bf16((a), (b), (c), 0, 0, 0)

__device__ __forceinline__ short f2bf(float f) {
  union { float f; unsigned u; } v; v.f = f;
  unsigned r = v.u + 0x7fffu + ((v.u >> 16) & 1u);   // RNE to bf16
  return (short)(r >> 16);
}
__device__ __forceinline__ unsigned pack2(float lo, float hi) {
  return (unsigned)(unsigned short)f2bf(lo) | ((unsigned)(unsigned short)f2bf(hi) << 16);
}

// ---------------------------------------------------------------------------
// K1: QKV projection (unchanged — ~35µs vs ~25µs floor; revisit after K2)
// ---------------------------------------------------------------------------
__global__ __launch_bounds__(256) void qkv_kernel(
    const float* __restrict__ x,
    const float* __restrict__ wq, const float* __restrict__ bq,
    const float* __restrict__ wk, const float* __restrict__ bk,
    const float* __restrict__ wv, const float* __restrict__ bv,
    short* __restrict__ Q, short* __restrict__ K, short* __restrict__ V)
{
  __shared__ alignas(16) short xs[64 * 256];
  __shared__ alignas(16) short ws[3 * 64 * 64];
  __shared__ float bs[3 * 64];

  const int t    = threadIdx.x;
  const int b    = blockIdx.x >> 6;
  const int pt   = blockIdx.x & 63;
  const int pix0 = pt << 8;
  const float* xb = x + ((size_t)b << 20);

  #pragma unroll
  for (int i = 0; i < 16; ++i) {
    int f4 = i * 256 + t;
    int c  = f4 >> 6;
    int p4 = (f4 & 63) << 2;
    const float4 v = *reinterpret_cast<const float4*>(xb + c * 16384 + pix0 + p4);
    short* d = &xs[c * 256 + p4];
    d[0] = f2bf(v.x); d[1] = f2bf(v.y); d[2] = f2bf(v.z); d[3] = f2bf(v.w);
  }
  {
    #pragma unroll
    for (int i = 0; i < 16; ++i) {
      int idx = i * 256 + t;
      int e = idx >> 6, c = idx & 63;
      int d = e * 64 + (c ^ ((e & 7) << 3));
      ws[d]        = f2bf(wq[idx]);
      ws[d + 4096] = f2bf(wk[idx]);
      ws[d + 8192] = f2bf(wv[idx]);
    }
    if (t < 192) bs[t] = (t < 64) ? bq[t] : ((t < 128) ? bk[t - 64] : bv[t - 128]);
  }
  __syncthreads();

  const int lane = t & 63;
  const int wid  = t >> 6;
  const int p0   = wid << 6;
  const int l15  = lane & 15;
  const int lg   = lane >> 4;

  short8 bfrag[4][2];
  #pragma unroll
  for (int nt = 0; nt < 4; ++nt) {
    int pix = p0 + nt * 16 + l15;
    #pragma unroll
    for (int ks = 0; ks < 2; ++ks) {
      int cb = ks * 32 + (lg << 3);
      short8 f;
      #pragma unroll
      for (int j = 0; j < 8; ++j) f[j] = xs[(cb + j) * 256 + pix];
      bfrag[nt][ks] = f;
    }
  }

  #pragma unroll
  for (int m = 0; m < 3; ++m) {
    short* op = (m == 0) ? Q : ((m == 1) ? K : V);
    short8 afrag[4][2];
    #pragma unroll
    for (int mt = 0; mt < 4; ++mt) {
      int e = mt * 16 + l15;
      #pragma unroll
      for (int ks = 0; ks < 2; ++ks) {
        int cb8 = (ks * 4 + lg) ^ (e & 7);
        afrag[mt][ks] = *reinterpret_cast<const short8*>(&ws[m * 4096 + e * 64 + cb8 * 8]);
      }
    }
    #pragma unroll
    for (int mt = 0; mt < 4; ++mt) {
      #pragma unroll
      for (int nt = 0; nt < 4; ++nt) {
        f32x4 acc = {0.f, 0.f, 0.f, 0.f};
        acc = MFMA16(afrag[mt][0], bfrag[nt][0], acc);
        acc = MFMA16(afrag[mt][1], bfrag[nt][1], acc);
        int e_base = mt * 16 + (lg << 2);
        int pix = pix0 + p0 + nt * 16 + l15;
        #pragma unroll
        for (int r = 0; r < 4; ++r) {
          int e = e_base + r;
          float val = acc[r] + bs[m * 64 + e];
          op[(((size_t)b * 64 + e) << 14) + pix] = f2bf(val);
        }
      }
    }
  }
}

// ---------------------------------------------------------------------------
// K2: per-(b,e) attention.  512 thr = 8 waves, 16-row strip each.
// 64KB LDS (2 x 32KB) -> 2 blocks/CU for cross-block phase overlap.
// T1/T2^T parked in packed-bf16 regs; Q/K transposed in place via
// colgather->regs->barrier->b128 rows; V cols gathered FROM GLOBAL
// (coalesced 128B row sweeps, L2/L3-hot) under S2's MFMA.
//   B1: Q -> QT -> T1 -> TV      B2: K -> KT -> VT -> T2^T
// 7 barriers.  All matmuls: NT swizzled ds_read_b128.
// ---------------------------------------------------------------------------
__global__ __launch_bounds__(512) void attn_kernel(
    const short* __restrict__ Qg, const short* __restrict__ Kg,
    const short* __restrict__ Vg, float* __restrict__ out)
{
  __shared__ alignas(16) short B1[128 * 128];    // 32KB
  __shared__ alignas(16) short B2[128 * 128];    // 32KB

  const int t = threadIdx.x;
  const size_t base = (size_t)blockIdx.x << 14;

  // coalesced global rows -> swizzled LDS rows
  auto stage = [&](short* dst, const short* src) {
    #pragma unroll
    for (int i = 0; i < 4; ++i) {
      int eb  = i * 512 + t;
      int row = eb >> 4;
      int cb  = eb & 15;
      float4 v = *reinterpret_cast<const float4*>(src + (eb << 3));
      *reinterpret_cast<float4*>(dst + row * 128 + ((cb ^ (row & 15)) << 3)) = v;
    }
  };

  const int w  = t & 127;        // transpose: owned column
  const int rb = (t >> 7) << 5;  // transpose: row-block base (0/32/64/96)

  // swizzled LDS column gather -> 16 packed bf16 pairs (reads: 64-lane
  // sweep of 64 consecutive cols in one row = 2-way, free)
  auto colgather = [&](const short* src, unsigned* p) {
    #pragma unroll
    for (int k2 = 0; k2 < 16; ++k2) {
      int r0 = rb + 2 * k2;
      int r1 = r0 + 1;
      unsigned a  = (unsigned short)src[r0 * 128 + (w ^ ((r0 & 15) << 3))];
      unsigned b_ = (unsigned short)src[r1 * 128 + (w ^ ((r1 & 15) << 3))];
      p[k2] = a | (b_ << 16);
    }
  };
  // packed col regs -> transposed row of dst (b128, swizzled)
  auto t_write = [&](short* dst, const unsigned* p) {
    const int w15 = w & 15;
    #pragma unroll
    for (int k8 = 0; k8 < 4; ++k8) {
      int hb = (rb >> 3) + k8;
      *reinterpret_cast<short8*>(&dst[w * 128 + ((hb ^ w15) << 3)]) =
          *reinterpret_cast<const short8*>(&p[k8 * 4]);
    }
  };

  const int lane = t & 63;
  const int wid  = t >> 6;
  const int m0   = wid << 4;
  const int l15  = lane & 15;
  const int lg   = lane >> 4;

  auto ldfrag = [&](const short* buf, int rowbase, int ks) -> short8 {
    int row = rowbase + l15;
    int cb  = (ks * 4 + lg) ^ (row & 15);
    return *reinterpret_cast<const short8*>(&buf[row * 128 + cb * 8]);
  };

  f32x4 acc[8];

  auto matmul = [&](const short* bufA, const short* bufB) {
    short8 af[4];
    #pragma unroll
    for (int ks = 0; ks < 4; ++ks) af[ks] = ldfrag(bufA, m0, ks);
    #pragma unroll
    for (int n = 0; n < 8; ++n) {
      f32x4 a = {0.f, 0.f, 0.f, 0.f};
      #pragma unroll
      for (int ks = 0; ks < 4; ++ks) a = MFMA16(af[ks], ldfrag(bufB, n * 16, ks), a);
      acc[n] = a;
    }
  };

  auto softmax_pack = [&](unsigned* pk) {
    #pragma unroll
    for (int r = 0; r < 4; ++r) {
      float mx = acc[0][r];
      #pragma unroll
      for (int n = 1; n < 8; ++n) mx = fmaxf(mx, acc[n][r]);
      mx = fmaxf(mx, __shfl_xor(mx, 1));
      mx = fmaxf(mx, __shfl_xor(mx, 2));
      mx = fmaxf(mx, __shfl_xor(mx, 4));
      mx = fmaxf(mx, __shfl_xor(mx, 8));
      float p[8]; float s = 0.f;
      #pragma unroll
      for (int n = 0; n < 8; ++n) { p[n] = __expf((acc[n][r] - mx) * 0.125f); s += p[n]; }
      s += __shfl_xor(s, 1); s += __shfl_xor(s, 2);
      s += __shfl_xor(s, 4); s += __shfl_xor(s, 8);
      float inv = 1.0f / s;
      #pragma unroll
      for (int np = 0; np < 4; ++np)
        pk[r * 4 + np] = pack2(p[2 * np] * inv, p[2 * np + 1] * inv);
    }
  };

  // packed strip -> own 16 rows, conflict-free (row&15 granule swizzle)
  auto store_pk = [&](short* dst, const unsigned* pk) {
    #pragma unroll
    for (int r = 0; r < 4; ++r) {
      int row = m0 + (lg << 2) + r;
      int sw  = (row & 15) << 3;
      #pragma unroll
      for (int np = 0; np < 4; ++np) {
        unsigned v = pk[r * 4 + np];
        int c0 = (2 * np) * 16 + l15;
        int c1 = c0 + 16;
        dst[row * 128 + (c0 ^ sw)] = (short)(v & 0xffff);
        dst[row * 128 + (c1 ^ sw)] = (short)(v >> 16);
      }
    }
  };

  unsigned t1[16], t2[16];

  // 1. stage Q, K
  stage(B1, Qg + base);
  stage(B2, Kg + base);
  __syncthreads();                               // sync0

  // 2. S1 = Q K^T -> softmax -> t1; Q/K column gathers (still pre-overwrite)
  matmul(B1, B2);
  softmax_pack(t1);
  unsigned qc[16], kc[16];
  colgather(B1, qc);
  colgather(B2, kc);
  __syncthreads();                               // syncA: all B1/B2 reads done

  // 3. in-place transpose: B1=QT, B2=KT
  t_write(B1, qc);
  t_write(B2, kc);
  __syncthreads();                               // syncB

  // 4. V column gather from GLOBAL (coalesced 128B sweeps, L2/L3-hot;
  //    latency hides under S2); S2^T = K^T Q -> softmax -> t2
  unsigned vc[16];
  {
    const short* Vsrc = Vg + base;
    #pragma unroll
    for (int k2 = 0; k2 < 16; ++k2) {
      unsigned a  = (unsigned short)Vsrc[(rb + 2 * k2) * 128 + w];
      unsigned b_ = (unsigned short)Vsrc[(rb + 2 * k2 + 1) * 128 + w];
      vc[k2] = a | (b_ << 16);
    }
  }
  matmul(B2, B1);                                // A = KT strips, B = QT
  softmax_pack(t2);
  __syncthreads();                               // syncC: S2 reads done

  // 5. VT -> B2; T1 -> B1
  t_write(B2, vc);
  store_pk(B1, t1);
  __syncthreads();                               // syncD

  // 6. TV = T1 · V (B-frags = VT rows) -> own strip of B1 (own-strip safe)
  matmul(B1, B2);
  #pragma unroll
  for (int n = 0; n < 8; ++n) {
    #pragma unroll
    for (int r = 0; r < 4; ++r) {
      int row = m0 + (lg << 2) + r;
      int col = n * 16 + l15;
      B1[row * 128 + (col ^ ((row & 15) << 3))] = f2bf(acc[n][r]);
    }
  }
  __syncthreads();                               // syncE: all VT reads done

  // 7. T2^T -> B2
  store_pk(B2, t2);
  __syncthreads();                               // syncF

  // 8. OUT = TV · T2 = TV · (T2^T)^T -> fp32 global
  float* ob = out + base;
  #pragma unroll
  for (int n = 0; n < 8; ++n) {
    f32x4 a = {0.f, 0.f, 0.f, 0.f};
    #pragma unroll
    for (int ks = 0; ks < 4; ++ks)
      a = MFMA16(ldfrag(B1, m0, ks), ldfrag(B2, n * 16, ks), a);
    #pragma unroll
    for (int r = 0; r < 4; ++r) {
      int row = m0 + (lg << 2) + r;
      ob[row * 128 + n * 16 + l15] = a[r];
    }
  }
}

extern "C" void kernel_launch(void* const* d_in, const int* in_sizes, int n_in,
                              void* d_out, int out_size, void* d_ws, size_t ws_size,
                              hipStream_t stream) {
  const float* x  = (const float*)d_in[0];
  const float* wq = (const float*)d_in[1];
  const float* bq = (const float*)d_in[2];
  const float* wk = (const float*)d_in[3];
  const float* bk = (const float*)d_in[4];
  const float* wv = (const float*)d_in[5];
  const float* bv = (const float*)d_in[6];

  const size_t N = (size_t)16 * 64 * 128 * 128;
  short* Q = (short*)d_ws;
  short* K = Q + N;
  short* V = K + N;

  qkv_kernel<<<1024, 256, 0, stream>>>(x, wq, bq, wk, bk, wv, bv, Q, K, V);
  attn_kernel<<<1024, 512, 0, stream>>>(Q, K, V, (float*)d_out);
}